// Round 6
// baseline (2701.388 us; speedup 1.0000x reference)
//
#include <hip/hip_runtime.h>
#include <hip/hip_bf16.h>
#include <cstdint>

typedef __attribute__((ext_vector_type(4))) float f32x4;
typedef _Float16 f16x8 __attribute__((ext_vector_type(8)));

#define BN_EPS 1e-5f

// ---------------- fp32 -> fp16 cast (vectorized, 8 elems/thread) ----------------
__global__ __launch_bounds__(256)
void cast_f32_f16(const float* __restrict__ src, _Float16* __restrict__ dst, int n8) {
    int i = blockIdx.x * blockDim.x + threadIdx.x;
    if (i >= n8) return;
    const float4* s4 = (const float4*)src;
    float4 a = s4[2 * (size_t)i];
    float4 b = s4[2 * (size_t)i + 1];
    f16x8 h;
    h[0] = (_Float16)a.x; h[1] = (_Float16)a.y; h[2] = (_Float16)a.z; h[3] = (_Float16)a.w;
    h[4] = (_Float16)b.x; h[5] = (_Float16)b.y; h[6] = (_Float16)b.z; h[7] = (_Float16)b.w;
    *(f16x8*)(dst + 8 * (size_t)i) = h;
}

// async global->LDS, 16B per lane, wave-uniform LDS base
__device__ __forceinline__ void async16(const char* g, _Float16* l) {
    __builtin_amdgcn_global_load_lds(
        (const __attribute__((address_space(1))) unsigned int*)(uintptr_t)g,
        (__attribute__((address_space(3))) unsigned int*)(uintptr_t)l,
        16, 0, 0);
}

// ================= 256x256 tile, BK=32, 4-buffer, wave-group STAGGERED schedule ==========
// 8 waves in 2 role-groups (wr0: wid0-3, wr1: wid4-7; round-robin wave->SIMD puts one of
// each group per SIMD). Per K-tile, 4 barrier-windows; in each window one group issues its
// ds_reads (+2 global_load_lds) while the other group runs a 16-MFMA cluster, so the LDS
// port and the MFMA pipes are both busy in every window (breaks the all-wave convoy).
// wr1 runs one quadrant ahead (prologue pre-read). Per-wave vmcnt ledgers:
//   steady: wr0 issues its 4 tile-loads at W1/W3 -> vmcnt(8) leaves kt+3(4)+kt+2(4), kt+1 done.
//           wr1 issues at W2/W4 -> vmcnt(6) leaves kt+3(2)+kt+2(4), kt+1 done.
// Buffer (kt+3)&3 == (kt-1)&3 re-staged only after all reads of kt-1 completed (per-group
// reads end by W4(kt-1) < stage issues in kt's windows). Tail waits 4 -> 0 -> 0.

struct KFrags { f16x8 a[4]; f16x8 b[4]; };

__device__ __forceinline__ void readQ0(KFrags& f, const char* ab, const char* bb,
                                       int aoff, int boff) {
    #pragma unroll
    for (int n = 0; n < 4; ++n) f.b[n] = *(const f16x8*)(bb + boff + n * 1024);
    #pragma unroll
    for (int m = 0; m < 4; ++m) f.a[m] = *(const f16x8*)(ab + aoff + m * 1024);
}
__device__ __forceinline__ void readQ1(KFrags& f, const char* ab, int aoff) {
    #pragma unroll
    for (int m = 0; m < 4; ++m) f.a[m] = *(const f16x8*)(ab + aoff + (4 + m) * 1024);
}
__device__ __forceinline__ void mfmaQ(const KFrags& f, f32x4 (&acc)[8][4], int mbase) {
    __builtin_amdgcn_s_setprio(1);
    #pragma unroll
    for (int m = 0; m < 4; ++m)
        #pragma unroll
        for (int n = 0; n < 4; ++n)
            acc[mbase + m][n] = __builtin_amdgcn_mfma_f32_16x16x32_f16(f.a[m], f.b[n], acc[mbase + m][n], 0, 0, 0);
    __builtin_amdgcn_s_setprio(0);
}

template<int WAITSEL, bool STAGE, bool LAST>
__device__ __forceinline__ void ktile(
    int kt, _Float16* As, _Float16* Bs,
    const char* a0, const char* a1, const char* b0, const char* b1,
    int wid, int wr, int aoff, int boff, KFrags& f, f32x4 (&acc)[8][4])
{
    const char* ab = (const char*)As + ((kt & 3) << 14);
    const char* bb = (const char*)Bs + ((kt & 3) << 14);

    // ---- W1: wr0 reads q0 (+stage A-half) | wr1 MFMA q0 (pre-read last W4) ----
    if (wr == 0) {
        readQ0(f, ab, bb, aoff, boff);
        if (STAGE) {
            _Float16* dA = As + ((kt + 3) & 3) * 8192 + wid * 512;
            async16(a0 + (size_t)(kt + 3) * 64, dA);
            async16(a1 + (size_t)(kt + 3) * 64, dA + 4096);
        }
    } else {
        mfmaQ(f, acc, 0);
    }
    __builtin_amdgcn_s_barrier();

    // ---- W2: wr0 MFMA q0 | wr1 reads q1 (+stage A-half) ----
    if (wr == 0) {
        mfmaQ(f, acc, 0);
    } else {
        readQ1(f, ab, aoff);
        if (STAGE) {
            _Float16* dA = As + ((kt + 3) & 3) * 8192 + wid * 512;
            async16(a0 + (size_t)(kt + 3) * 64, dA);
            async16(a1 + (size_t)(kt + 3) * 64, dA + 4096);
        }
    }
    __builtin_amdgcn_s_barrier();

    // ---- W3: wr0 reads q1 (+stage B-half) | wr1 MFMA q1 ----
    if (wr == 0) {
        readQ1(f, ab, aoff);
        if (STAGE) {
            _Float16* dB = Bs + ((kt + 3) & 3) * 8192 + wid * 512;
            async16(b0 + (size_t)(kt + 3) * 64, dB);
            async16(b1 + (size_t)(kt + 3) * 64, dB + 4096);
        }
    } else {
        mfmaQ(f, acc, 4);
    }
    if (WAITSEL == 2) {
        if (wr == 0) { asm volatile("s_waitcnt vmcnt(8)" ::: "memory"); }
        else         { asm volatile("s_waitcnt vmcnt(6)" ::: "memory"); }
    } else if (WAITSEL == 1) {
        asm volatile("s_waitcnt vmcnt(4)" ::: "memory");
    } else {
        asm volatile("s_waitcnt vmcnt(0)" ::: "memory");
    }
    __builtin_amdgcn_s_barrier();

    // ---- W4: wr0 MFMA q1 | wr1 reads q0 of kt+1 (+stage B-half) ----
    if (wr == 0) {
        mfmaQ(f, acc, 4);
    } else if (!LAST) {
        const char* abn = (const char*)As + (((kt + 1) & 3) << 14);
        const char* bbn = (const char*)Bs + (((kt + 1) & 3) << 14);
        readQ0(f, abn, bbn, aoff, boff);
        if (STAGE) {
            _Float16* dB = Bs + ((kt + 3) & 3) * 8192 + wid * 512;
            async16(b0 + (size_t)(kt + 3) * 64, dB);
            async16(b1 + (size_t)(kt + 3) * 64, dB + 4096);
        }
    }
    __builtin_amdgcn_s_barrier();
}

__global__ __launch_bounds__(512, 2)
void gemm_gbn_kernel(const _Float16* __restrict__ A,
                     const _Float16* __restrict__ Bw,
                     const float* __restrict__ priors,
                     const float* __restrict__ gamma,
                     const float* __restrict__ beta,
                     float* __restrict__ Z,
                     int M, int N, int K)
{
    __shared__ __align__(16) _Float16 As[4 * 8192];   // 64 KB
    __shared__ __align__(16) _Float16 Bs[4 * 8192];   // 64 KB

    const int tid  = threadIdx.x;
    const int lane = tid & 63;
    const int wid  = tid >> 6;     // 0..7
    const int wr   = wid >> 2;     // role group 0/1; rows wr*128.. (one virtual batch)
    const int wc   = wid & 3;      // 0..3  (64-col slice)
    const int fr   = lane & 15;
    const int kg   = lane >> 4;

    // XCD-aware bijective swizzle (nwg = 512, divisible by 8)
    const int bid = blockIdx.x;
    const int swz = (bid & 7) * 64 + (bid >> 3);
    const int row0 = (swz >> 2) * 256;
    const int col0 = (swz & 3) * 256;

    // staging sources: T2 pre-permuted source col-slot (lane&3)^((lane>>3)&3) (16B units)
    const int sperm = ((lane & 3) ^ ((lane >> 3) & 3)) * 16;
    const char* a0 = (const char*)A  + (size_t)(row0 + (tid >> 2)) * (size_t)K * 2 + sperm;
    const char* a1 = a0 + (size_t)128 * K * 2;
    const char* b0 = (const char*)Bw + (size_t)(col0 + (tid >> 2)) * (size_t)K * 2 + sperm;
    const char* b1 = b0 + (size_t)128 * K * 2;

    // LDS fragment byte offsets ([256][32] f16, 64B rows), T2-swizzled (verified 0-conflict).
    int aoff = (wr * 128 + fr) * 64 + kg * 16;
    aoff ^= ((aoff >> 7) & 3) << 4;
    int boff = (wc * 64 + fr) * 64 + kg * 16;
    boff ^= ((boff >> 7) & 3) << 4;

    f32x4 acc[8][4];
    #pragma unroll
    for (int m = 0; m < 8; ++m)
        #pragma unroll
        for (int n = 0; n < 4; ++n)
            acc[m][n] = (f32x4)0.0f;

    // prologue: stage K-tiles 0,1,2 -> buffers 0,1,2
    #pragma unroll
    for (int t = 0; t < 3; ++t) {
        _Float16* dA = As + t * 8192 + wid * 512;
        async16(a0 + (size_t)t * 64, dA);
        async16(a1 + (size_t)t * 64, dA + 4096);
        _Float16* dB = Bs + t * 8192 + wid * 512;
        async16(b0 + (size_t)t * 64, dB);
        async16(b1 + (size_t)t * 64, dB + 4096);
    }
    asm volatile("s_waitcnt vmcnt(8)" ::: "memory");   // tile 0 resident; 1,2 in flight
    __builtin_amdgcn_s_barrier();

    KFrags f;
    if (wr == 1) readQ0(f, (const char*)As, (const char*)Bs, aoff, boff);  // pre-read tile 0

    const int nt = K >> 5;                 // 64 K-tiles
    for (int kt = 0; kt < nt - 3; ++kt)    // stages kt+3 up to nt-1
        ktile<2, true,  false>(kt, As, Bs, a0, a1, b0, b1, wid, wr, aoff, boff, f, acc);
    ktile<1, false, false>(nt - 3, As, Bs, a0, a1, b0, b1, wid, wr, aoff, boff, f, acc);
    ktile<0, false, false>(nt - 2, As, Bs, a0, a1, b0, b1, wid, wr, aoff, boff, f, acc);
    ktile<0, false, true >(nt - 1, As, Bs, a0, a1, b0, b1, wid, wr, aoff, boff, f, acc);

    // ---- fused Ghost BatchNorm + priors epilogue (wave-local: wr half = one VBS) ----
    #pragma unroll
    for (int n = 0; n < 4; ++n) {
        float s1 = 0.f, s2 = 0.f;
        #pragma unroll
        for (int m = 0; m < 8; ++m)
            #pragma unroll
            for (int j = 0; j < 4; ++j) {
                float v = acc[m][n][j];
                s1 += v; s2 += v * v;
            }
        s1 += __shfl_xor(s1, 16); s2 += __shfl_xor(s2, 16);
        s1 += __shfl_xor(s1, 32); s2 += __shfl_xor(s2, 32);
        float mean = s1 * (1.f / 128.f);
        float var  = s2 * (1.f / 128.f) - mean * mean;
        float rstd = rsqrtf(var + BN_EPS);
        const int c = col0 + wc * 64 + n * 16 + fr;
        float g = gamma[c] * rstd;
        float b = beta[c] - mean * g;
        #pragma unroll
        for (int m = 0; m < 8; ++m)
            #pragma unroll
            for (int j = 0; j < 4; ++j) {
                int r = row0 + wr * 128 + m * 16 + kg * 4 + j;
                size_t off = (size_t)r * N + c;
                Z[off] = (acc[m][n][j] * g + b) * priors[off];
            }
    }
}

// ---------------- sparsemax: one wave per row of 1024, exact Michelot projection ----------------
__device__ __forceinline__ float waveSum(float v) {
    #pragma unroll
    for (int off = 32; off > 0; off >>= 1) v += __shfl_xor(v, off);
    return v;
}

__global__ __launch_bounds__(256)
void sparsemax_kernel(float* __restrict__ Z) {
    const int lane = threadIdx.x & 63;
    const int wid  = threadIdx.x >> 6;
    const size_t row = (size_t)blockIdx.x * 4 + wid;
    float4* zr4 = (float4*)(Z + row * 1024);

    float p[16];
    #pragma unroll
    for (int j = 0; j < 4; ++j) {
        float4 t = zr4[lane * 4 + j];
        p[4 * j + 0] = t.x; p[4 * j + 1] = t.y; p[4 * j + 2] = t.z; p[4 * j + 3] = t.w;
    }

    float s = 0.f;
    #pragma unroll
    for (int i = 0; i < 16; ++i) s += p[i];
    s = waveSum(s);

    float kc  = 1024.f;
    float tau = (s - 1.f) * (1.f / 1024.f);
    for (int it = 0; it < 64; ++it) {
        float s2 = 0.f, c2 = 0.f;
        #pragma unroll
        for (int i = 0; i < 16; ++i) {
            if (p[i] > tau) { s2 += p[i]; c2 += 1.f; }
        }
        s2 = waveSum(s2); c2 = waveSum(c2);
        if (c2 == kc) break;        // support stable -> tau exact
        kc = c2;
        tau = (s2 - 1.f) / c2;
    }

    #pragma unroll
    for (int j = 0; j < 4; ++j) {
        float4 o;
        o.x = fmaxf(p[4 * j + 0] - tau, 0.f);
        o.y = fmaxf(p[4 * j + 1] - tau, 0.f);
        o.z = fmaxf(p[4 * j + 2] - tau, 0.f);
        o.w = fmaxf(p[4 * j + 3] - tau, 0.f);
        zr4[lane * 4 + j] = o;
    }
}

extern "C" void kernel_launch(void* const* d_in, const int* in_sizes, int n_in,
                              void* d_out, int out_size, void* d_ws, size_t ws_size,
                              hipStream_t stream)
{
    const float* priors = (const float*)d_in[0];
    const float* feat   = (const float*)d_in[1];
    const float* W      = (const float*)d_in[2];
    const float* gamma  = (const float*)d_in[3];
    const float* beta   = (const float*)d_in[4];
    float* out = (float*)d_out;

    const int Nf = in_sizes[3];              // 1024
    const int Kf = in_sizes[2] / Nf;         // 2048
    const int Mr = in_sizes[1] / Kf;         // 32768

    _Float16* Ah = (_Float16*)d_ws;                                  // M*K*2 = 128 MB
    _Float16* Wh = (_Float16*)((char*)d_ws + (size_t)Mr * Kf * 2);   // N*K*2 =   4 MB

    {
        int n8 = Mr * (Kf / 8);
        cast_f32_f16<<<(n8 + 255) / 256, 256, 0, stream>>>(feat, Ah, n8);
    }
    {
        int n8 = Nf * (Kf / 8);
        cast_f32_f16<<<(n8 + 255) / 256, 256, 0, stream>>>(W, Wh, n8);
    }

    int nblk = (Mr / 256) * (Nf / 256);      // 512, divisible by 8
    gemm_gbn_kernel<<<nblk, 512, 0, stream>>>(Ah, Wh, priors, gamma, beta, out, Mr, Nf, Kf);

    sparsemax_kernel<<<Mr / 4, 256, 0, stream>>>(out);
}

// Round 7
// 371.798 us; speedup vs baseline: 7.2657x; 7.2657x over previous
//
#include <hip/hip_runtime.h>
#include <hip/hip_bf16.h>
#include <cstdint>

typedef __attribute__((ext_vector_type(4))) float f32x4;
typedef _Float16 f16x8 __attribute__((ext_vector_type(8)));

#define BN_EPS 1e-5f

// ---------------- fp32 -> fp16 cast (vectorized, 8 elems/thread) ----------------
__global__ __launch_bounds__(256)
void cast_f32_f16(const float* __restrict__ src, _Float16* __restrict__ dst, int n8) {
    int i = blockIdx.x * blockDim.x + threadIdx.x;
    if (i >= n8) return;
    const float4* s4 = (const float4*)src;
    float4 a = s4[2 * (size_t)i];
    float4 b = s4[2 * (size_t)i + 1];
    f16x8 h;
    h[0] = (_Float16)a.x; h[1] = (_Float16)a.y; h[2] = (_Float16)a.z; h[3] = (_Float16)a.w;
    h[4] = (_Float16)b.x; h[5] = (_Float16)b.y; h[6] = (_Float16)b.z; h[7] = (_Float16)b.w;
    *(f16x8*)(dst + 8 * (size_t)i) = h;
}

// async global->LDS, 16B per lane, wave-uniform LDS base
__device__ __forceinline__ void async16(const char* g, _Float16* l) {
    __builtin_amdgcn_global_load_lds(
        (const __attribute__((address_space(1))) unsigned int*)(uintptr_t)g,
        (__attribute__((address_space(3))) unsigned int*)(uintptr_t)l,
        16, 0, 0);
}

// ================= 128x128 tile, BK=32, 3-buffer, multi-block-per-CU GEMM =================
// 4 waves (2x2), per-wave 64x64 out. LDS: 3 x (A 8KB + B 8KB) = 48KB + 2KB red -> 3 blocks/CU
// (12 waves/CU): independent blocks decorrelate barrier phases so LDS-read bursts of one
// block overlap MFMA bursts of another (m114 mechanism). Depth-2 prefetch, vmcnt(4) counted:
//   at kt body: outstanding = kt+1 (4 loads); stage kt+2 -> 8; after MFMAs wait vmcnt(4)
//   retires kt+1 -> resident for kt+1's reads. Buffer (kt+2)%3 == (kt-1)%3: reads of kt-1
//   drained before its closing barrier, which precedes this stage. Tail: vmcnt(0) at nt-2.
// LDS read swizzle (verified 0-conflict in r3/r4): byte ^= ((byte>>7)&3)<<4, i.e. slot XOR
// row bits 1-2; staging keeps LDS linear and pre-permutes the global k-slot per lane.

__device__ __forceinline__ void stageTile(int t, _Float16* As, _Float16* Bs,
                                          const char* a0, const char* a1,
                                          const char* b0, const char* b1, int wid) {
    _Float16* dA = As + (t % 3) * 4096 + wid * 512;
    async16(a0 + (size_t)t * 64, dA);            // rows 0-63
    async16(a1 + (size_t)t * 64, dA + 2048);     // rows 64-127
    _Float16* dB = Bs + (t % 3) * 4096 + wid * 512;
    async16(b0 + (size_t)t * 64, dB);
    async16(b1 + (size_t)t * 64, dB + 2048);
}

template<int WAITSEL, bool STAGE, bool BAR>
__device__ __forceinline__ void ktile(
    int kt, _Float16* As, _Float16* Bs,
    const char* a0, const char* a1, const char* b0, const char* b1,
    int wid, int aoff, int boff, f32x4 (&acc)[4][4])
{
    if (STAGE) stageTile(kt + 2, As, Bs, a0, a1, b0, b1, wid);
    const char* ab = (const char*)As + (kt % 3) * 8192;
    const char* bb = (const char*)Bs + (kt % 3) * 8192;
    f16x8 a[4], b[4];
    #pragma unroll
    for (int n = 0; n < 4; ++n) b[n] = *(const f16x8*)(bb + boff + n * 1024);
    #pragma unroll
    for (int m = 0; m < 4; ++m) a[m] = *(const f16x8*)(ab + aoff + m * 1024);
    __builtin_amdgcn_s_setprio(1);
    #pragma unroll
    for (int m = 0; m < 4; ++m)
        #pragma unroll
        for (int n = 0; n < 4; ++n)
            acc[m][n] = __builtin_amdgcn_mfma_f32_16x16x32_f16(a[m], b[n], acc[m][n], 0, 0, 0);
    __builtin_amdgcn_s_setprio(0);
    if (WAITSEL == 2)      { asm volatile("s_waitcnt vmcnt(4)" ::: "memory"); }
    else if (WAITSEL == 1) { asm volatile("s_waitcnt vmcnt(0)" ::: "memory"); }
    if (BAR) __builtin_amdgcn_s_barrier();
}

__global__ __launch_bounds__(256)
void gemm_gbn_kernel(const _Float16* __restrict__ A,
                     const _Float16* __restrict__ Bw,
                     const float* __restrict__ priors,
                     const float* __restrict__ gamma,
                     const float* __restrict__ beta,
                     float* __restrict__ Z,
                     int M, int N, int K)
{
    __shared__ __align__(16) _Float16 As[3 * 4096];   // 24 KB
    __shared__ __align__(16) _Float16 Bs[3 * 4096];   // 24 KB
    __shared__ float red[2][128][2];                  //  2 KB

    const int tid  = threadIdx.x;
    const int lane = tid & 63;
    const int wid  = tid >> 6;     // 0..3
    const int wr   = wid >> 1;     // 0..1 (64-row slice)
    const int wc   = wid & 1;      // 0..1 (64-col slice)
    const int fr   = lane & 15;
    const int kg   = lane >> 4;

    // XCD-aware bijective swizzle: 2048 blocks -> 8 chunks of 256.
    // Within a chunk, col-block varies fastest -> A-panel reused by 8 consecutive blocks,
    // full B (4 MB) hot in each XCD's L2.
    const int bid = blockIdx.x;
    const int swz = (bid & 7) * 256 + (bid >> 3);
    const int row0 = (swz >> 3) * 128;
    const int col0 = (swz & 7) * 128;

    // staging sources: thread t covers row t>>2 (+64 on 2nd issue); pre-permuted k-slot
    // sperm = (t&3)^((t>>3)&3) so that linear LDS dest == swizzled layout.
    const int sperm = ((tid & 3) ^ ((tid >> 3) & 3)) * 16;
    const char* a0 = (const char*)A  + (size_t)(row0 + (tid >> 2)) * (size_t)K * 2 + sperm;
    const char* a1 = a0 + (size_t)64 * K * 2;
    const char* b0 = (const char*)Bw + (size_t)(col0 + (tid >> 2)) * (size_t)K * 2 + sperm;
    const char* b1 = b0 + (size_t)64 * K * 2;

    // fragment byte offsets ([128][32] f16, 64B rows), swizzled; XOR value = ((fr>>1)&3)<<4
    // is constant per lane, so +m*1024 / +n*1024 commute with the swizzle.
    int aoff = (wr * 64 + fr) * 64 + kg * 16;
    aoff ^= ((aoff >> 7) & 3) << 4;
    int boff = (wc * 64 + fr) * 64 + kg * 16;
    boff ^= ((boff >> 7) & 3) << 4;

    f32x4 acc[4][4];
    #pragma unroll
    for (int m = 0; m < 4; ++m)
        #pragma unroll
        for (int n = 0; n < 4; ++n)
            acc[m][n] = (f32x4)0.0f;

    // prologue: stage tiles 0,1; wait tile 0 (vmcnt(4) leaves tile 1 in flight)
    stageTile(0, As, Bs, a0, a1, b0, b1, wid);
    stageTile(1, As, Bs, a0, a1, b0, b1, wid);
    asm volatile("s_waitcnt vmcnt(4)" ::: "memory");
    __builtin_amdgcn_s_barrier();

    const int nt = K >> 5;                 // 64 K-tiles
    for (int kt = 0; kt < nt - 2; ++kt)    // stages kt+2 up to nt-1
        ktile<2, true,  true >(kt, As, Bs, a0, a1, b0, b1, wid, aoff, boff, acc);
    ktile<1, false, true >(nt - 2, As, Bs, a0, a1, b0, b1, wid, aoff, boff, acc);
    ktile<0, false, false>(nt - 1, As, Bs, a0, a1, b0, b1, wid, aoff, boff, acc);

    // ---- fused Ghost BatchNorm + priors epilogue (block = one 128-row virtual batch) ----
    #pragma unroll
    for (int n = 0; n < 4; ++n) {
        float s1 = 0.f, s2 = 0.f;
        #pragma unroll
        for (int m = 0; m < 4; ++m)
            #pragma unroll
            for (int j = 0; j < 4; ++j) {
                float v = acc[m][n][j];
                s1 += v; s2 += v * v;
            }
        s1 += __shfl_xor(s1, 16); s2 += __shfl_xor(s2, 16);
        s1 += __shfl_xor(s1, 32); s2 += __shfl_xor(s2, 32);
        if (lane < 16) {
            red[wr][wc * 64 + n * 16 + lane][0] = s1;
            red[wr][wc * 64 + n * 16 + lane][1] = s2;
        }
    }
    __syncthreads();

    const int rowb = row0 + wr * 64 + kg * 4;
    #pragma unroll
    for (int n = 0; n < 4; ++n) {
        const int c = wc * 64 + n * 16 + fr;
        float s1 = red[0][c][0] + red[1][c][0];
        float s2 = red[0][c][1] + red[1][c][1];
        float mean = s1 * (1.f / 128.f);
        float var  = s2 * (1.f / 128.f) - mean * mean;
        float rstd = rsqrtf(var + BN_EPS);
        float g = gamma[col0 + c] * rstd;
        float b = beta[col0 + c] - mean * g;
        #pragma unroll
        for (int m = 0; m < 4; ++m)
            #pragma unroll
            for (int j = 0; j < 4; ++j) {
                int r = rowb + m * 16 + j;
                size_t off = (size_t)r * N + col0 + c;
                Z[off] = (acc[m][n][j] * g + b) * priors[off];
            }
    }
}

// ---------------- sparsemax: one wave per row of 1024, exact Michelot projection ----------------
__device__ __forceinline__ float waveSum(float v) {
    #pragma unroll
    for (int off = 32; off > 0; off >>= 1) v += __shfl_xor(v, off);
    return v;
}

__global__ __launch_bounds__(256)
void sparsemax_kernel(float* __restrict__ Z) {
    const int lane = threadIdx.x & 63;
    const int wid  = threadIdx.x >> 6;
    const size_t row = (size_t)blockIdx.x * 4 + wid;
    float4* zr4 = (float4*)(Z + row * 1024);

    float p[16];
    #pragma unroll
    for (int j = 0; j < 4; ++j) {
        float4 t = zr4[lane * 4 + j];
        p[4 * j + 0] = t.x; p[4 * j + 1] = t.y; p[4 * j + 2] = t.z; p[4 * j + 3] = t.w;
    }

    float s = 0.f;
    #pragma unroll
    for (int i = 0; i < 16; ++i) s += p[i];
    s = waveSum(s);

    float kc  = 1024.f;
    float tau = (s - 1.f) * (1.f / 1024.f);
    for (int it = 0; it < 64; ++it) {
        float s2 = 0.f, c2 = 0.f;
        #pragma unroll
        for (int i = 0; i < 16; ++i) {
            if (p[i] > tau) { s2 += p[i]; c2 += 1.f; }
        }
        s2 = waveSum(s2); c2 = waveSum(c2);
        if (c2 == kc) break;        // support stable -> tau exact
        kc = c2;
        tau = (s2 - 1.f) / c2;
    }

    #pragma unroll
    for (int j = 0; j < 4; ++j) {
        float4 o;
        o.x = fmaxf(p[4 * j + 0] - tau, 0.f);
        o.y = fmaxf(p[4 * j + 1] - tau, 0.f);
        o.z = fmaxf(p[4 * j + 2] - tau, 0.f);
        o.w = fmaxf(p[4 * j + 3] - tau, 0.f);
        zr4[lane * 4 + j] = o;
    }
}

extern "C" void kernel_launch(void* const* d_in, const int* in_sizes, int n_in,
                              void* d_out, int out_size, void* d_ws, size_t ws_size,
                              hipStream_t stream)
{
    const float* priors = (const float*)d_in[0];
    const float* feat   = (const float*)d_in[1];
    const float* W      = (const float*)d_in[2];
    const float* gamma  = (const float*)d_in[3];
    const float* beta   = (const float*)d_in[4];
    float* out = (float*)d_out;

    const int Nf = in_sizes[3];              // 1024
    const int Kf = in_sizes[2] / Nf;         // 2048
    const int Mr = in_sizes[1] / Kf;         // 32768

    _Float16* Ah = (_Float16*)d_ws;                                  // M*K*2 = 128 MB
    _Float16* Wh = (_Float16*)((char*)d_ws + (size_t)Mr * Kf * 2);   // N*K*2 =   4 MB

    {
        int n8 = Mr * (Kf / 8);
        cast_f32_f16<<<(n8 + 255) / 256, 256, 0, stream>>>(feat, Ah, n8);
    }
    {
        int n8 = Nf * (Kf / 8);
        cast_f32_f16<<<(n8 + 255) / 256, 256, 0, stream>>>(W, Wh, n8);
    }

    int nblk = (Mr / 128) * (Nf / 128);      // 2048, divisible by 8
    gemm_gbn_kernel<<<nblk, 256, 0, stream>>>(Ah, Wh, priors, gamma, beta, out, Mr, Nf, Kf);

    sparsemax_kernel<<<Mr / 4, 256, 0, stream>>>(out);
}